// Round 9
// baseline (918.017 us; speedup 1.0000x reference)
//
#include <hip/hip_runtime.h>
#include <math.h>

typedef unsigned short u16;
typedef __bf16 bf16x8 __attribute__((ext_vector_type(8)));
typedef float f32x4 __attribute__((ext_vector_type(4)));

// Problem constants
#define BB 4
#define TT 1000
#define PP 300
#define CC 512
#define DD 256
#define HH 8
#define DH 64
#define LL 1300
#define FF 2048
#define H3 1536
#define VTS 1304   // padded j-stride for transposed V

// ---------------- workspace layout (float offsets) ----------------
#define OFF_STEP 64L
#define OFF_HB   2624L
#define OFF_S0   8192L
#define OFF_S1   (OFF_S0 + 2662400L)
#define OFF_FS   (OFF_S1 + 2662400L)
#define OFF_X    (OFF_FS + 2662400L)
#define OFF_BIG  (OFF_X  + 2662400L)
#define OFF_VT   (OFF_BIG + 2662400L)
#define OFF_Z    (OFF_BIG + 7987200L)
#define OFF_XNH  (OFF_Z   + 1331200L)
#define OFF_AOH  (OFF_XNH + 1331200L)
#define OFF_FSH  (OFF_AOH + 1331200L)
#define OFF_WT   (OFF_FSH + 1331200L)
// WT sub-offsets (ushort units)
#define WT_QKV 0L
#define WT_WO  3145728L
#define WT_W1  4194304L
#define WT_W2  8388608L
#define WT_SK  12582912L
#define WT_OUT 12845056L
#define WT_SPEC 12976128L
#define WT_COND 13107200L
#define WT_PR   13238272L

__device__ __forceinline__ u16 f2bf(float f) {
    unsigned u = __float_as_uint(f);
    unsigned r = (u + 0x7FFFu + ((u >> 16) & 1u)) >> 16;
    return (u16)r;
}

__device__ __forceinline__ void gld_lds16(const void* g, void* l) {
    __builtin_amdgcn_global_load_lds((const __attribute__((address_space(1))) void*)g,
                                     (__attribute__((address_space(3))) void*)l, 16, 0, 0);
}

// stage a 64x64 bf16 tile into LDS [2][64][32] half-tiles with XOR swizzle
__device__ __forceinline__ void stage64(const u16* __restrict__ gbase, long rstride,
                                        u16* __restrict__ lds, int tid) {
    int row = tid >> 2, pblk = tid & 3;
    int lblk = pblk ^ ((row >> 1) & 3);
    #pragma unroll
    for (int p = 0; p < 2; p++) {
        gld_lds16(gbase + (long)row * rstride + p * 32 + lblk * 8,
                  lds + ((long)(p * 256 + tid)) * 8);
    }
}

// row-clamped variant (A-operand, M not multiple of 64)
__device__ __forceinline__ void stage64c(const u16* __restrict__ gbase, long rstride,
                                         int row0, int maxRow,
                                         u16* __restrict__ lds, int tid) {
    int row = tid >> 2, pblk = tid & 3;
    int lblk = pblk ^ ((row >> 1) & 3);
    int rg = row0 + row; if (rg > maxRow) rg = maxRow;
    const u16* src = gbase + (long)rg * rstride;
    #pragma unroll
    for (int p = 0; p < 2; p++) {
        gld_lds16(src + p * 32 + lblk * 8,
                  lds + ((long)(p * 256 + tid)) * 8);
    }
}

// ---------------- mask length extraction (dtype-robust) ----------------
__global__ void k_meta(const unsigned* __restrict__ pmW,
                       const unsigned* __restrict__ xmW,
                       int* __restrict__ meta)
{
    __shared__ int modeS;
    __shared__ int cnt[8];
    int tid = threadIdx.x;
    if (tid < 8) cnt[tid] = 0;
    if (tid == 0) modeS = 0;
    __syncthreads();
    int byteFlag = 0;
    for (int j = tid; j < PP; j += 256) if (pmW[j] > 1u) byteFlag = 1;
    for (int j = tid; j < TT; j += 256) if (xmW[j] > 1u) byteFlag = 1;
    if (byteFlag) atomicOr(&modeS, 1);
    __syncthreads();
    if ((modeS & 1) == 0) {
        int i64Flag = 0;
        for (int j = tid; j < 4 * PP - 1; j += 256) {
            if ((j % PP) == PP - 1) continue;
            if (pmW[j] == 1u && pmW[j + 1] == 0u) i64Flag = 1;
        }
        if (i64Flag) atomicOr(&modeS, 2);
    }
    __syncthreads();
    int mode = modeS;
    const unsigned char* pmB = (const unsigned char*)pmW;
    const long long*     pmL = (const long long*)pmW;
    const int*           pmI = (const int*)pmW;
    const unsigned char* xmB = (const unsigned char*)xmW;
    const long long*     xmL = (const long long*)xmW;
    const int*           xmI = (const int*)xmW;
    for (int idx = tid; idx < BB * PP; idx += 256) {
        int b = idx / PP;
        bool z = (mode & 1) ? (pmB[idx] == 0) : (mode & 2) ? (pmL[idx] == 0) : (pmI[idx] == 0);
        if (z) atomicAdd(&cnt[b], 1);
    }
    for (int idx = tid; idx < BB * TT; idx += 256) {
        int b = idx / TT;
        bool z = (mode & 1) ? (xmB[idx] == 0) : (mode & 2) ? (xmL[idx] == 0) : (xmI[idx] == 0);
        if (z) atomicAdd(&cnt[4 + b], 1);
    }
    __syncthreads();
    if (tid < 8) meta[tid] = cnt[tid];
    if (tid == 8) meta[8] = mode;
}

// ---------------- diffusion-step embedding MLP ----------------
__global__ __launch_bounds__(256) void k_step1(const float* __restrict__ dsin,
    const float* __restrict__ W1, const float* __restrict__ b1, float* __restrict__ hbuf)
{
    __shared__ float emb[DD];
    __shared__ float red[256];
    int row = blockIdx.y, tid = threadIdx.x;
    int n0 = blockIdx.x * 64;
    float t = (row < BB) ? dsin[row] : 0.f;
    if (tid < 128) {
        const float c = 9.210340371976184f / 127.f;
        float f = expf(-c * (float)tid);
        float a = t * f;
        emb[tid] = sinf(a);
        emb[tid + 128] = cosf(a);
    }
    __syncthreads();
    int n = n0 + (tid & 63);
    int k0 = (tid >> 6) * 64;
    float acc = 0.f;
    #pragma unroll 8
    for (int k = 0; k < 64; k++)
        acc += emb[k0 + k] * W1[(long)(k0 + k) * (4 * DD) + n];
    red[tid] = acc;
    __syncthreads();
    if (tid < 64) {
        float a2 = red[tid] + red[tid + 64] + red[tid + 128] + red[tid + 192] + b1[n];
        float sp = fmaxf(a2, 0.f) + log1pf(expf(-fabsf(a2)));
        hbuf[(long)row * (4 * DD) + n] = a2 * tanhf(sp);
    }
}

__global__ __launch_bounds__(256) void k_step2(const float* __restrict__ hbuf,
    const float* __restrict__ W2, const float* __restrict__ b2, float* __restrict__ outbuf)
{
    __shared__ float h1[4 * DD];
    __shared__ float red[256];
    int row = blockIdx.y, tid = threadIdx.x;
    int n0 = blockIdx.x * 64;
    #pragma unroll
    for (int p = 0; p < 4; p++) h1[tid + p * 256] = hbuf[(long)row * (4 * DD) + tid + p * 256];
    __syncthreads();
    int n = n0 + (tid & 63);
    int k0 = (tid >> 6) * 256;
    float acc = 0.f;
    #pragma unroll 8
    for (int k = 0; k < 256; k++)
        acc += h1[k0 + k] * W2[(long)(k0 + k) * CC + n];
    red[tid] = acc;
    __syncthreads();
    if (tid < 64)
        outbuf[(long)row * CC + n] = red[tid] + red[tid + 64] + red[tid + 128] + red[tid + 192] + b2[n];
}

// ---------------- weight transpose + bf16 cast ----------------
__global__ __launch_bounds__(256) void k_wcast(const float* __restrict__ W, u16* __restrict__ WT,
                                               int K, int N, long inStride, long outStride)
{
    __shared__ float t[64][65];
    int n0 = blockIdx.x * 64, k0 = blockIdx.y * 64;
    long z = blockIdx.z;
    const float* Wz = W + z * inStride;
    u16* WTz = WT + z * outStride;
    int tid = threadIdx.x;
    #pragma unroll
    for (int p = 0; p < 16; p++) {
        int idx = tid + p * 256;
        int rk = idx >> 6, cn = idx & 63;
        t[rk][cn] = Wz[(long)(k0 + rk) * N + n0 + cn];
    }
    __syncthreads();
    #pragma unroll
    for (int p = 0; p < 8; p++) {
        int idx = tid + p * 256;
        int n = idx >> 5, k2 = (idx & 31) * 2;
        ushort2 u;
        u.x = f2bf(t[k2][n]);
        u.y = f2bf(t[k2 + 1][n]);
        *(ushort2*)&WTz[(long)(n0 + n) * K + k0 + k2] = u;
    }
}

// transpose+cast with N bounds (activations)
__global__ __launch_bounds__(256) void k_acast(const float* __restrict__ Win, u16* __restrict__ Out,
                                               int K, int N, long inStride, long outStride)
{
    __shared__ float t[64][65];
    int n0 = blockIdx.x * 64, k0 = blockIdx.y * 64;
    long z = blockIdx.z;
    const float* Wz = Win + z * inStride;
    u16* Oz = Out + z * outStride;
    int tid = threadIdx.x;
    #pragma unroll
    for (int p = 0; p < 16; p++) {
        int idx = tid + p * 256;
        int rk = idx >> 6, cn = idx & 63;
        int nn = n0 + cn; if (nn >= N) nn = N - 1;
        t[rk][cn] = Wz[(long)(k0 + rk) * N + nn];
    }
    __syncthreads();
    #pragma unroll
    for (int p = 0; p < 8; p++) {
        int idx = tid + p * 256;
        int nn = idx >> 5, k2 = (idx & 31) * 2;
        if (n0 + nn < N) {
            ushort2 u;
            u.x = f2bf(t[k2][nn]);
            u.y = f2bf(t[k2 + 1][nn]);
            *(ushort2*)&Oz[(long)(n0 + nn) * K + k0 + k2] = u;
        }
    }
}

// elementwise fp32 -> bf16 cast
__global__ void k_cast(const float4* __restrict__ in, ushort4* __restrict__ out, int n4)
{
    int i = blockIdx.x * 256 + threadIdx.x;
    if (i < n4) {
        float4 v = in[i];
        ushort4 u;
        u.x = f2bf(v.x); u.y = f2bf(v.y); u.z = f2bf(v.z); u.w = f2bf(v.w);
        out[i] = u;
    }
}

// zero fp32 region
__global__ void k_zero(float4* __restrict__ p, int n4)
{
    int i = blockIdx.x * 256 + threadIdx.x;
    if (i < n4) p[i] = (float4){0.f, 0.f, 0.f, 0.f};
}

// ---------------- bf16 MFMA GEMM, 64x128 tile, BK=64, XCD-swizzled grid ----------------
// grid: x = 8*Nb (k=x&7 selects XCD-aligned m residue, n=x>>3), y = m-groups (m = 8y+k), z = splitK.
// Blocks with the same m land on the same XCD (id%8 heuristic) -> per-XCD L2 keeps A slice + full B.
template<int RELU, int OUTBF, int ATOMIC>
__global__ __launch_bounds__(256) void k_mm64(
    const u16* __restrict__ A, const u16* __restrict__ Bt,
    const float* __restrict__ bias, void* __restrict__ Cp,
    int M, int N, int K, int Ks)
{
    int mb = blockIdx.y * 8 + (blockIdx.x & 7);
    int m0 = mb * 64;
    if (m0 >= M) return;
    int n0 = (blockIdx.x >> 3) * 128;
    __shared__ u16 As[4096];
    __shared__ u16 Bs[2][4096];
    int tid = threadIdx.x;
    int w = tid >> 6, lane = tid & 63;
    int q = lane >> 4, r = lane & 15;
    int wm = w & 1, wn = w >> 1;
    int kz = blockIdx.z;
    int kbase = kz * Ks;
    f32x4 acc[2][4] = {};
    int ar0 = wm * 32 + r;
    int ar1 = ar0 + 16;
    int aoff0 = ar0 * 32 + (q ^ ((ar0 >> 1) & 3)) * 8;
    int aoff1 = ar1 * 32 + (q ^ ((ar1 >> 1) & 3)) * 8;

    for (int k0 = kbase; k0 < kbase + Ks; k0 += 64) {
        __syncthreads();
        stage64c(A + k0, K, m0, M - 1, As, tid);
        stage64(Bt + (long)n0 * K + k0, K, Bs[0], tid);
        stage64(Bt + (long)(n0 + 64) * K + k0, K, Bs[1], tid);
        __syncthreads();
        #pragma unroll
        for (int kh = 0; kh < 2; kh++) {
            bf16x8 a0 = *(const bf16x8*)&As[kh * 2048 + aoff0];
            bf16x8 a1 = *(const bf16x8*)&As[kh * 2048 + aoff1];
            #pragma unroll
            for (int ni = 0; ni < 4; ni++) {
                int rr = ni * 16 + r;
                bf16x8 bv = *(const bf16x8*)&Bs[wn][kh * 2048 + rr * 32 + (q ^ ((rr >> 1) & 3)) * 8];
                acc[0][ni] = __builtin_amdgcn_mfma_f32_16x16x32_bf16(a0, bv, acc[0][ni], 0, 0, 0);
                acc[1][ni] = __builtin_amdgcn_mfma_f32_16x16x32_bf16(a1, bv, acc[1][ni], 0, 0, 0);
            }
        }
    }

    #pragma unroll
    for (int ni = 0; ni < 4; ni++) {
        int col = n0 + wn * 64 + ni * 16 + r;
        float bs = (!ATOMIC || kz == 0) ? bias[col] : 0.f;
        #pragma unroll
        for (int mi = 0; mi < 2; mi++) {
            #pragma unroll
            for (int reg = 0; reg < 4; reg++) {
                int grow = m0 + wm * 32 + mi * 16 + q * 4 + reg;
                if (grow >= M) continue;
                long off = (long)grow * N + col;
                float v = acc[mi][ni][reg] + bs;
                if (RELU) v = fmaxf(v, 0.f);
                if (ATOMIC)      atomicAdd((float*)Cp + off, v);
                else if (OUTBF)  ((u16*)Cp)[off] = f2bf(v);
                else             ((float*)Cp)[off] = v;
            }
        }
    }
}

// ---------------- QKV GEMM (XCD-swizzled): Q,K natural bf16 + V transposed ----------------
__global__ __launch_bounds__(256) void k_mmqkv64(
    const u16* __restrict__ A, const u16* __restrict__ Bt,
    const float* __restrict__ bias, u16* __restrict__ qkh, u16* __restrict__ vt,
    int M, int K)
{
    int mb = blockIdx.y * 8 + (blockIdx.x & 7);
    int m0 = mb * 64;
    if (m0 >= M) return;
    int n0 = (blockIdx.x >> 3) * 128;
    __shared__ u16 As[4096];
    __shared__ u16 Bs[2][4096];
    int tid = threadIdx.x;
    int w = tid >> 6, lane = tid & 63;
    int q = lane >> 4, r = lane & 15;
    int wm = w & 1, wn = w >> 1;
    f32x4 acc[2][4] = {};
    int ar0 = wm * 32 + r;
    int ar1 = ar0 + 16;
    int aoff0 = ar0 * 32 + (q ^ ((ar0 >> 1) & 3)) * 8;
    int aoff1 = ar1 * 32 + (q ^ ((ar1 >> 1) & 3)) * 8;

    for (int k0 = 0; k0 < K; k0 += 64) {
        __syncthreads();
        stage64c(A + k0, K, m0, M - 1, As, tid);
        stage64(Bt + (long)n0 * K + k0, K, Bs[0], tid);
        stage64(Bt + (long)(n0 + 64) * K + k0, K, Bs[1], tid);
        __syncthreads();
        #pragma unroll
        for (int kh = 0; kh < 2; kh++) {
            bf16x8 a0 = *(const bf16x8*)&As[kh * 2048 + aoff0];
            bf16x8 a1 = *(const bf16x8*)&As[kh * 2048 + aoff1];
            #pragma unroll
            for (int ni = 0; ni < 4; ni++) {
                int rr = ni * 16 + r;
                bf16x8 bv = *(const bf16x8*)&Bs[wn][kh * 2048 + rr * 32 + (q ^ ((rr >> 1) & 3)) * 8];
                acc[0][ni] = __builtin_amdgcn_mfma_f32_16x16x32_bf16(a0, bv, acc[0][ni], 0, 0, 0);
                acc[1][ni] = __builtin_amdgcn_mfma_f32_16x16x32_bf16(a1, bv, acc[1][ni], 0, 0, 0);
            }
        }
    }

    #pragma unroll
    for (int ni = 0; ni < 4; ni++) {
        int col = n0 + wn * 64 + ni * 16 + r;
        float bs = bias[col];
        #pragma unroll
        for (int mi = 0; mi < 2; mi++) {
            #pragma unroll
            for (int reg = 0; reg < 4; reg++) {
                int grow = m0 + wm * 32 + mi * 16 + q * 4 + reg;
                if (grow >= M) continue;
                float v = acc[mi][ni][reg] + bs;
                if (col < 1024) {
                    qkh[(long)grow * 1024 + col] = f2bf(v);
                } else {
                    int c2 = col - 1024;
                    int hh = c2 >> 6, dd = c2 & 63;
                    int bq = grow / LL;
                    int jj = grow - bq * LL;
                    vt[(((long)(bq * HH + hh)) * 64 + dd) * VTS + jj] = f2bf(v);
                }
            }
        }
    }
}

// ---------------- MFMA flash attention, fixed-base softmax, XCD-swizzled (id%8 == head) ----------------
__global__ __launch_bounds__(256) void k_attn(const u16* __restrict__ qkh,
                                              const u16* __restrict__ vt,
                                              const int* __restrict__ meta,
                                              u16* __restrict__ aoh)
{
    __shared__ u16 Qs[4096], Ks[4096], Vts[4096], Ps[4096];
    int id = blockIdx.x;
    int h = id & 7;           // id%8 -> same head stays on one XCD (KV slice hot in its L2)
    int rest = id >> 3;       // [0, 84)
    int b = rest & 3;
    int qt = rest >> 2;       // [0, 21)
    int tid = threadIdx.x;
    int w = tid >> 6, lane = tid & 63;
    int q = lane >> 4, r = lane & 15;
    int kend = meta[b] + meta[4 + b];
    int q0 = qt * 64;

    stage64(qkh + ((long)(b * LL + q0)) * 1024 + h * DH, 1024, Qs, tid);

    float lsum[4] = {0.f, 0.f, 0.f, 0.f};
    f32x4 O[4] = {};

    int arow = w * 16 + r;
    int aoff = arow * 32 + (q ^ ((arow >> 1) & 3)) * 8;

    for (int j0 = 0; j0 < kend; j0 += 64) {
        __syncthreads();
        stage64(qkh + ((long)(b * LL + j0)) * 1024 + CC + h * DH, 1024, Ks, tid);
        stage64(vt + (((long)(b * HH + h)) * 64) * VTS + j0, VTS, Vts, tid);
        __syncthreads();

        f32x4 sacc[4] = {};
        #pragma unroll
        for (int kh = 0; kh < 2; kh++) {
            bf16x8 aq = *(const bf16x8*)&Qs[kh * 2048 + aoff];
            #pragma unroll
            for (int ni = 0; ni < 4; ni++) {
                int rn = ni * 16 + r;
                bf16x8 bk = *(const bf16x8*)&Ks[kh * 2048 + rn * 32 + (q ^ ((rn >> 1) & 3)) * 8];
                sacc[ni] = __builtin_amdgcn_mfma_f32_16x16x32_bf16(aq, bk, sacc[ni], 0, 0, 0);
            }
        }

        #pragma unroll
        for (int reg = 0; reg < 4; reg++) {
            int prow = w * 16 + q * 4 + reg;
            int psw = (prow >> 1) & 3;
            #pragma unroll
            for (int ni = 0; ni < 4; ni++) {
                int jg = j0 + r + 16 * ni;
                float p = (jg < kend) ? __expf(sacc[ni][reg] * 0.125f) : 0.f;
                lsum[reg] += p;
                int c = r + 16 * ni;
                Ps[(c >> 5) * 2048 + prow * 32 + ((((c & 31) >> 3)) ^ psw) * 8 + (c & 7)] = f2bf(p);
            }
        }

        #pragma unroll
        for (int kh = 0; kh < 2; kh++) {
            bf16x8 ap = *(const bf16x8*)&Ps[kh * 2048 + aoff];
            #pragma unroll
            for (int ni = 0; ni < 4; ni++) {
                int rn = ni * 16 + r;
                bf16x8 bv = *(const bf16x8*)&Vts[kh * 2048 + rn * 32 + (q ^ ((rn >> 1) & 3)) * 8];
                O[ni] = __builtin_amdgcn_mfma_f32_16x16x32_bf16(ap, bv, O[ni], 0, 0, 0);
            }
        }
    }

    #pragma unroll
    for (int reg = 0; reg < 4; reg++) {
        float l = lsum[reg];
        #pragma unroll
        for (int off = 1; off < 16; off <<= 1) l += __shfl_xor(l, off, 64);
        int qr = q0 + w * 16 + q * 4 + reg;
        if (qr >= LL) continue;
        float inv = 1.f / l;
        #pragma unroll
        for (int ni = 0; ni < 4; ni++)
            aoh[((long)(b * LL + qr)) * CC + h * DH + r + 16 * ni] = f2bf(O[ni][reg] * inv);
    }
}

// ---------------- pack ----------------
__global__ void k_pack(const float* __restrict__ spec_h, const float* __restrict__ cond_h,
                       const float* __restrict__ prompt_h, const float* __restrict__ stepbuf,
                       const int* __restrict__ meta, float* __restrict__ x)
{
    int j = blockIdx.x, b = blockIdx.y;
    int pl = meta[b], sl = meta[4 + b];
    int tid = threadIdx.x;
    int reg = (j < pl) ? 0 : ((j < pl + sl) ? 1 : 2);
    int pos = (reg == 0) ? j + 1 : ((reg == 1) ? j - pl + 1 : j - pl - sl + 1);
    const float c1 = 9.210340371976184f / 255.f;
    for (int c = tid; c < CC; c += 256) {
        int i = (c < 256) ? c : c - 256;
        float f = expf(-c1 * (float)i);
        float a = (float)pos * f;
        float v = (c < 256) ? sinf(a) : cosf(a);
        if (reg == 0) {
            v += prompt_h[((long)(b * PP + j)) * CC + c] + stepbuf[4 * CC + c];
        } else if (reg == 1) {
            int t = j - pl;
            v += spec_h[((long)(b * TT + t)) * CC + c] + cond_h[((long)(b * TT + t)) * CC + c]
               + stepbuf[b * CC + c];
        }
        x[((long)(b * LL + j)) * CC + c] = v;
    }
}

// ---------------- LayerNorm -> bf16 ----------------
__global__ __launch_bounds__(256) void k_ln(float* __restrict__ x, const float* __restrict__ skip,
                                            const float* __restrict__ g, const float* __restrict__ bb,
                                            u16* __restrict__ xnh)
{
    long row = blockIdx.x;
    float* xr = x + row * CC;
    int tid = threadIdx.x;
    float v0 = xr[tid], v1 = xr[tid + 256];
    if (skip) {
        const float rs2 = 0.7071067811865476f;
        v0 = (v0 + skip[row * CC + tid]) * rs2;
        v1 = (v1 + skip[row * CC + tid + 256]) * rs2;
        xr[tid] = v0; xr[tid + 256] = v1;
    }
    float s = v0 + v1;
    for (int off = 32; off; off >>= 1) s += __shfl_down(s, off, 64);
    __shared__ float red[4];
    int wid = tid >> 6, lane = tid & 63;
    if (lane == 0) red[wid] = s;
    __syncthreads();
    float mean = (red[0] + red[1] + red[2] + red[3]) * (1.f / (float)CC);
    float d0 = v0 - mean, d1 = v1 - mean;
    float q = d0 * d0 + d1 * d1;
    for (int off = 32; off; off >>= 1) q += __shfl_down(q, off, 64);
    __syncthreads();
    if (lane == 0) red[wid] = q;
    __syncthreads();
    float var = (red[0] + red[1] + red[2] + red[3]) * (1.f / (float)CC);
    float rstd = rsqrtf(var + 1e-5f);
    xnh[row * CC + tid]       = f2bf(d0 * rstd * g[tid] + bb[tid]);
    xnh[row * CC + tid + 256] = f2bf(d1 * rstd * g[tid + 256] + bb[tid + 256]);
}

// ---------------- fused skip-accum + next-layer ln1 ----------------
__global__ __launch_bounds__(256) void k_accum_ln(
    float* __restrict__ x, float* __restrict__ fsum, float* __restrict__ skipdst,
    const float* __restrict__ skip, int self,
    const float* __restrict__ g, const float* __restrict__ bb,
    u16* __restrict__ xnh, u16* __restrict__ fsh, int first, int last)
{
    long row = blockIdx.x;
    int tid = threadIdx.x;
    long o0 = row * CC + tid, o1 = o0 + 256;
    float v0 = x[o0], v1 = x[o1];
    float f0, f1;
    if (first) { f0 = v0; f1 = v1; }
    else { f0 = fsum[o0] + v0; f1 = fsum[o1] + v1; }
    fsum[o0] = f0; fsum[o1] = f1;
    if (skipdst) { skipdst[o0] = v0; skipdst[o1] = v1; }
    if (last) {
        fsh[o0] = f2bf(f0 * 0.5f);
        fsh[o1] = f2bf(f1 * 0.5f);
        return;
    }
    const float rs2 = 0.7071067811865476f;
    if (self) {
        v0 *= 1.4142135623730951f; v1 *= 1.4142135623730951f;
        x[o0] = v0; x[o1] = v1;
    } else if (skip) {
        v0 = (v0 + skip[o0]) * rs2; v1 = (v1 + skip[o1]) * rs2;
        x[o0] = v0; x[o1] = v1;
    }
    float s = v0 + v1;
    for (int off = 32; off; off >>= 1) s += __shfl_down(s, off, 64);
    __shared__ float red[4];
    int wid = tid >> 6, lane = tid & 63;
    if (lane == 0) red[wid] = s;
    __syncthreads();
    float mean = (red[0] + red[1] + red[2] + red[3]) * (1.f / (float)CC);
    float d0 = v0 - mean, d1 = v1 - mean;
    float qv = d0 * d0 + d1 * d1;
    for (int off = 32; off; off >>= 1) qv += __shfl_down(qv, off, 64);
    __syncthreads();
    if (lane == 0) red[wid] = qv;
    __syncthreads();
    float var = (red[0] + red[1] + red[2] + red[3]) * (1.f / (float)CC);
    float rstd = rsqrtf(var + 1e-5f);
    xnh[o0] = f2bf(d0 * rstd * g[tid] + bb[tid]);
    xnh[o1] = f2bf(d1 * rstd * g[tid + 256] + bb[tid + 256]);
}

// ---------------- final gather + transpose ----------------
__global__ void k_gather(const float* __restrict__ z, const int* __restrict__ meta,
                         float* __restrict__ out)
{
    int i = blockIdx.x * 256 + threadIdx.x;
    int b = i / (DD * TT);
    int rdt = i % (DD * TT);
    int d = rdt / TT, t = rdt % TT;
    long row = (long)b * LL + meta[b] + t;
    out[i] = z[row * DD + d];
}

extern "C" void kernel_launch(void* const* d_in, const int* in_sizes, int n_in,
                              void* d_out, int out_size, void* d_ws, size_t ws_size,
                              hipStream_t stream)
{
    const float* spec     = (const float*)d_in[0];
    const void*  x_mask   = d_in[1];
    const float* dstep_in = (const float*)d_in[2];
    const float* cond     = (const float*)d_in[3];
    const float* prompt   = (const float*)d_in[5];
    const void*  p_mask   = d_in[6];
    const float* spec_W   = (const float*)d_in[7];
    const float* spec_b   = (const float*)d_in[8];
    const float* cond_W   = (const float*)d_in[9];
    const float* cond_b   = (const float*)d_in[10];
    const float* prompt_W = (const float*)d_in[11];
    const float* prompt_b = (const float*)d_in[12];
    const float* mlp_W1   = (const float*)d_in[13];
    const float* mlp_b1   = (const float*)d_in[14];
    const float* mlp_W2   = (const float*)d_in[15];
    const float* mlp_b2   = (const float*)d_in[16];
    const float* out_W    = (const float*)d_in[17];
    const float* out_b    = (const float*)d_in[18];
    const float* skip_W   = (const float*)d_in[19];
    const float* skip_b   = (const float*)d_in[20];
    const float* Wqkv     = (const float*)d_in[21];
    const float* bqkv     = (const float*)d_in[22];
    const float* Wo       = (const float*)d_in[23];
    const float* bo       = (const float*)d_in[24];
    const float* ln1_g    = (const float*)d_in[25];
    const float* ln1_b    = (const float*)d_in[26];
    const float* ln2_g    = (const float*)d_in[27];
    const float* ln2_b    = (const float*)d_in[28];
    const float* ffn_W1   = (const float*)d_in[29];
    const float* ffn_b1   = (const float*)d_in[30];
    const float* ffn_W2   = (const float*)d_in[31];
    const float* ffn_b2   = (const float*)d_in[32];

    float* W  = (float*)d_ws;
    int* meta = (int*)d_ws;
    float* stepbuf = W + OFF_STEP;
    float* HB  = W + OFF_HB;
    float* S0  = W + OFF_S0;
    float* S1  = W + OFF_S1;
    float* FS  = W + OFF_FS;
    float* X   = W + OFF_X;
    u16*   QKHh = (u16*)(W + OFF_BIG);
    u16*   VTh  = (u16*)(W + OFF_VT);
    u16*   BIGh = (u16*)(W + OFF_BIG);
    u16*   SPECAh = (u16*)(W + OFF_BIG);
    u16*   CONDAh = (u16*)(W + OFF_BIG + 512000L);
    u16*   PRAh   = (u16*)(W + OFF_BIG + 1024000L);
    float* Z   = W + OFF_Z;
    u16*   XNh = (u16*)(W + OFF_XNH);
    u16*   AOh = (u16*)(W + OFF_AOH);
    u16*   FSh = (u16*)(W + OFF_FSH);
    u16*   WT  = (u16*)(W + OFF_WT);

    k_meta<<<1, 256, 0, stream>>>((const unsigned*)p_mask, (const unsigned*)x_mask, meta);
    k_step1<<<dim3(16, 5), 256, 0, stream>>>(dstep_in, mlp_W1, mlp_b1, HB);
    k_step2<<<dim3(8, 5), 256, 0, stream>>>(HB, mlp_W2, mlp_b2, stepbuf);

    // weight transpose+cast to bf16
    k_wcast<<<dim3(24, 8, 4), 256, 0, stream>>>(Wqkv, WT + WT_QKV, CC, H3, (long)CC * H3, (long)H3 * CC);
    k_wcast<<<dim3(8, 8, 4), 256, 0, stream>>>(Wo, WT + WT_WO, CC, CC, (long)CC * CC, (long)CC * CC);
    k_wcast<<<dim3(32, 8, 4), 256, 0, stream>>>(ffn_W1, WT + WT_W1, CC, FF, (long)CC * FF, (long)FF * CC);
    k_wcast<<<dim3(8, 32, 4), 256, 0, stream>>>(ffn_W2, WT + WT_W2, FF, CC, (long)FF * CC, (long)CC * FF);
    k_wcast<<<dim3(8, 8, 1), 256, 0, stream>>>(skip_W, WT + WT_SK, CC, CC, 0L, 0L);
    k_wcast<<<dim3(4, 8, 1), 256, 0, stream>>>(out_W, WT + WT_OUT, CC, DD, 0L, 0L);
    k_wcast<<<dim3(8, 4, 1), 256, 0, stream>>>(spec_W, WT + WT_SPEC, DD, CC, 0L, 0L);
    k_wcast<<<dim3(8, 4, 1), 256, 0, stream>>>(cond_W, WT + WT_COND, DD, CC, 0L, 0L);
    k_wcast<<<dim3(8, 4, 1), 256, 0, stream>>>(prompt_W, WT + WT_PR, DD, CC, 0L, 0L);

    // input projections (bf16 MFMA, XCD-swizzled grid: x = 8*Nb, y = ceil(Mb/8))
    k_acast<<<dim3(16, 4, 4), 256, 0, stream>>>(spec, SPECAh, DD, TT, (long)DD * TT, (long)TT * DD);
    k_acast<<<dim3(16, 4, 4), 256, 0, stream>>>(cond, CONDAh, DD, TT, (long)DD * TT, (long)TT * DD);
    k_cast<<<300, 256, 0, stream>>>((const float4*)prompt, (ushort4*)PRAh, BB * PP * DD / 4);
    k_mm64<0, 0, 0><<<dim3(32, 8), 256, 0, stream>>>(SPECAh, WT + WT_SPEC, spec_b, S0, BB * TT, CC, DD, DD);
    k_mm64<0, 0, 0><<<dim3(32, 8), 256, 0, stream>>>(CONDAh, WT + WT_COND, cond_b, S1, BB * TT, CC, DD, DD);
    k_mm64<0, 0, 0><<<dim3(32, 3), 256, 0, stream>>>(PRAh, WT + WT_PR, prompt_b, FS, BB * PP, CC, DD, DD);

    k_pack<<<dim3(LL, BB), 256, 0, stream>>>(S0, S1, FS, stepbuf, meta, X);

    const int Mrows = BB * LL; // 5200, Mb = 82 -> y = 11
    k_ln<<<Mrows, 256, 0, stream>>>(X, nullptr, ln1_g, ln1_b, XNh);
    for (int i = 0; i < 4; i++) {
        k_mmqkv64<<<dim3(96, 11), 256, 0, stream>>>(XNh, WT + WT_QKV + (long)i * CC * H3,
            bqkv + i * H3, QKHh, VTh, Mrows, CC);
        k_attn<<<672, 256, 0, stream>>>(QKHh, VTh, meta, AOh);
        // X += AOh @ Wo^T + bo   (split-K=2 atomic into residual X)
        k_mm64<0, 0, 1><<<dim3(32, 11, 2), 256, 0, stream>>>(AOh, WT + WT_WO + (long)i * CC * CC,
            bo + i * CC, X, Mrows, CC, CC, 256);
        k_ln<<<Mrows, 256, 0, stream>>>(X, nullptr, ln2_g + i * CC, ln2_b + i * CC, XNh);
        k_mm64<1, 1, 0><<<dim3(128, 11), 256, 0, stream>>>(XNh, WT + WT_W1 + (long)i * CC * FF,
            ffn_b1 + i * FF, BIGh, Mrows, FF, CC, CC);
        // X += BIGh @ W2^T + b2  (split-K=2 atomic)
        k_mm64<0, 0, 1><<<dim3(32, 11, 2), 256, 0, stream>>>(BIGh, WT + WT_W2 + (long)i * FF * CC,
            ffn_b2 + i * CC, X, Mrows, CC, FF, 1024);
        float* skipDst = (i == 0) ? S0 : nullptr;
        const float* skipNext = (i == 2) ? S0 : nullptr;
        int selfNext = (i == 1) ? 1 : 0;
        k_accum_ln<<<Mrows, 256, 0, stream>>>(X, FS, skipDst, skipNext, selfNext,
            ln1_g + (i + 1 < 4 ? (i + 1) : 0) * CC, ln1_b + (i + 1 < 4 ? (i + 1) : 0) * CC,
            XNh, FSh, i == 0, i == 3);
    }

    // y = relu((fsum*0.5) @ skip_W + skip_b) -> XNh (bf16), direct store
    k_mm64<1, 1, 0><<<dim3(32, 11), 256, 0, stream>>>(FSh, WT + WT_SK, skip_b, XNh, Mrows, CC, CC, CC);
    // z = y @ out_W + out_b  (split-K=2 atomic into zeroed Z)
    k_zero<<<1300, 256, 0, stream>>>((float4*)Z, 332800);
    k_mm64<0, 0, 1><<<dim3(16, 11, 2), 256, 0, stream>>>(XNh, WT + WT_OUT, out_b, Z, Mrows, DD, CC, 256);

    k_gather<<<4000, 256, 0, stream>>>(Z, meta, (float*)d_out);
    (void)in_sizes; (void)n_in; (void)out_size; (void)ws_size;
}

// Round 10
// 896.097 us; speedup vs baseline: 1.0245x; 1.0245x over previous
//
#include <hip/hip_runtime.h>
#include <math.h>

typedef unsigned short u16;
typedef __bf16 bf16x8 __attribute__((ext_vector_type(8)));
typedef float f32x4 __attribute__((ext_vector_type(4)));

// Problem constants
#define BB 4
#define TT 1000
#define PP 300
#define CC 512
#define DD 256
#define HH 8
#define DH 64
#define LL 1300
#define FF 2048
#define H3 1536
#define VTS 1304

// ---------------- workspace layout (float offsets) ----------------
#define OFF_STEP 64L
#define OFF_HB   2624L
#define OFF_S0   8192L
#define OFF_S1   (OFF_S0 + 2662400L)
#define OFF_FS   (OFF_S1 + 2662400L)
#define OFF_X    (OFF_FS + 2662400L)
#define OFF_BIG  (OFF_X  + 2662400L)
#define OFF_VT   (OFF_BIG + 2662400L)
#define OFF_Z    (OFF_BIG + 7987200L)
#define OFF_XNH  (OFF_Z   + 1331200L)
#define OFF_AOH  (OFF_XNH + 1331200L)
#define OFF_FSH  (OFF_AOH + 1331200L)
#define OFF_WT   (OFF_FSH + 1331200L)
// WT sub-offsets (ushort units)
#define WT_QKV 0L
#define WT_WO  3145728L
#define WT_W1  4194304L
#define WT_W2  8388608L
#define WT_SK  12582912L
#define WT_OUT 12845056L
#define WT_SPEC 12976128L
#define WT_COND 13107200L
#define WT_PR   13238272L

__device__ __forceinline__ u16 f2bf(float f) {
    unsigned u = __float_as_uint(f);
    unsigned r = (u + 0x7FFFu + ((u >> 16) & 1u)) >> 16;
    return (u16)r;
}

__device__ __forceinline__ void gld_lds16(const void* g, void* l) {
    __builtin_amdgcn_global_load_lds((const __attribute__((address_space(1))) void*)g,
                                     (__attribute__((address_space(3))) void*)l, 16, 0, 0);
}

// stage a 64x64 bf16 tile into LDS [2][64][32] half-tiles with XOR swizzle
__device__ __forceinline__ void stage64(const u16* __restrict__ gbase, long rstride,
                                        u16* __restrict__ lds, int tid) {
    int row = tid >> 2, pblk = tid & 3;
    int lblk = pblk ^ ((row >> 1) & 3);
    #pragma unroll
    for (int p = 0; p < 2; p++) {
        gld_lds16(gbase + (long)row * rstride + p * 32 + lblk * 8,
                  lds + ((long)(p * 256 + tid)) * 8);
    }
}

// row-clamped variant (A-operand, M not multiple of 64)
__device__ __forceinline__ void stage64c(const u16* __restrict__ gbase, long rstride,
                                         int row0, int maxRow,
                                         u16* __restrict__ lds, int tid) {
    int row = tid >> 2, pblk = tid & 3;
    int lblk = pblk ^ ((row >> 1) & 3);
    int rg = row0 + row; if (rg > maxRow) rg = maxRow;
    const u16* src = gbase + (long)rg * rstride;
    #pragma unroll
    for (int p = 0; p < 2; p++) {
        gld_lds16(src + p * 32 + lblk * 8,
                  lds + ((long)(p * 256 + tid)) * 8);
    }
}

// ---------------- mask length extraction (dtype-robust) ----------------
__global__ void k_meta(const unsigned* __restrict__ pmW,
                       const unsigned* __restrict__ xmW,
                       int* __restrict__ meta)
{
    __shared__ int modeS;
    __shared__ int cnt[8];
    int tid = threadIdx.x;
    if (tid < 8) cnt[tid] = 0;
    if (tid == 0) modeS = 0;
    __syncthreads();
    int byteFlag = 0;
    for (int j = tid; j < PP; j += 256) if (pmW[j] > 1u) byteFlag = 1;
    for (int j = tid; j < TT; j += 256) if (xmW[j] > 1u) byteFlag = 1;
    if (byteFlag) atomicOr(&modeS, 1);
    __syncthreads();
    if ((modeS & 1) == 0) {
        int i64Flag = 0;
        for (int j = tid; j < 4 * PP - 1; j += 256) {
            if ((j % PP) == PP - 1) continue;
            if (pmW[j] == 1u && pmW[j + 1] == 0u) i64Flag = 1;
        }
        if (i64Flag) atomicOr(&modeS, 2);
    }
    __syncthreads();
    int mode = modeS;
    const unsigned char* pmB = (const unsigned char*)pmW;
    const long long*     pmL = (const long long*)pmW;
    const int*           pmI = (const int*)pmW;
    const unsigned char* xmB = (const unsigned char*)xmW;
    const long long*     xmL = (const long long*)xmW;
    const int*           xmI = (const int*)xmW;
    for (int idx = tid; idx < BB * PP; idx += 256) {
        int b = idx / PP;
        bool z = (mode & 1) ? (pmB[idx] == 0) : (mode & 2) ? (pmL[idx] == 0) : (pmI[idx] == 0);
        if (z) atomicAdd(&cnt[b], 1);
    }
    for (int idx = tid; idx < BB * TT; idx += 256) {
        int b = idx / TT;
        bool z = (mode & 1) ? (xmB[idx] == 0) : (mode & 2) ? (xmL[idx] == 0) : (xmI[idx] == 0);
        if (z) atomicAdd(&cnt[4 + b], 1);
    }
    __syncthreads();
    if (tid < 8) meta[tid] = cnt[tid];
    if (tid == 8) meta[8] = mode;
}

// ---------------- diffusion-step embedding MLP ----------------
__global__ __launch_bounds__(256) void k_step1(const float* __restrict__ dsin,
    const float* __restrict__ W1, const float* __restrict__ b1, float* __restrict__ hbuf)
{
    __shared__ float emb[DD];
    __shared__ float red[256];
    int row = blockIdx.y, tid = threadIdx.x;
    int n0 = blockIdx.x * 64;
    float t = (row < BB) ? dsin[row] : 0.f;
    if (tid < 128) {
        const float c = 9.210340371976184f / 127.f;
        float f = expf(-c * (float)tid);
        float a = t * f;
        emb[tid] = sinf(a);
        emb[tid + 128] = cosf(a);
    }
    __syncthreads();
    int n = n0 + (tid & 63);
    int k0 = (tid >> 6) * 64;
    float acc = 0.f;
    #pragma unroll 8
    for (int k = 0; k < 64; k++)
        acc += emb[k0 + k] * W1[(long)(k0 + k) * (4 * DD) + n];
    red[tid] = acc;
    __syncthreads();
    if (tid < 64) {
        float a2 = red[tid] + red[tid + 64] + red[tid + 128] + red[tid + 192] + b1[n];
        float sp = fmaxf(a2, 0.f) + log1pf(expf(-fabsf(a2)));
        hbuf[(long)row * (4 * DD) + n] = a2 * tanhf(sp);
    }
}

__global__ __launch_bounds__(256) void k_step2(const float* __restrict__ hbuf,
    const float* __restrict__ W2, const float* __restrict__ b2, float* __restrict__ outbuf)
{
    __shared__ float h1[4 * DD];
    __shared__ float red[256];
    int row = blockIdx.y, tid = threadIdx.x;
    int n0 = blockIdx.x * 64;
    #pragma unroll
    for (int p = 0; p < 4; p++) h1[tid + p * 256] = hbuf[(long)row * (4 * DD) + tid + p * 256];
    __syncthreads();
    int n = n0 + (tid & 63);
    int k0 = (tid >> 6) * 256;
    float acc = 0.f;
    #pragma unroll 8
    for (int k = 0; k < 256; k++)
        acc += h1[k0 + k] * W2[(long)(k0 + k) * CC + n];
    red[tid] = acc;
    __syncthreads();
    if (tid < 64)
        outbuf[(long)row * CC + n] = red[tid] + red[tid + 64] + red[tid + 128] + red[tid + 192] + b2[n];
}

// ---------------- fused weight transpose+cast: all 9 weights in ONE launch ----------------
__device__ __forceinline__ void wcast_tile(const float* __restrict__ Wz, u16* __restrict__ WTz,
                                           int K, int N, int n0, int k0, int tid)
{
    __shared__ float t[64][65];
    #pragma unroll
    for (int p = 0; p < 16; p++) {
        int idx = tid + p * 256;
        int rk = idx >> 6, cn = idx & 63;
        t[rk][cn] = Wz[(long)(k0 + rk) * N + n0 + cn];
    }
    __syncthreads();
    #pragma unroll
    for (int p = 0; p < 8; p++) {
        int idx = tid + p * 256;
        int n = idx >> 5, k2 = (idx & 31) * 2;
        ushort2 u;
        u.x = f2bf(t[k2][n]);
        u.y = f2bf(t[k2 + 1][n]);
        *(ushort2*)&WTz[(long)(n0 + n) * K + k0 + k2] = u;
    }
}

// jobs: 0 qkv, 1 wo, 2 w1, 3 w2, 4 skip, 5 out, 6 spec, 7 cond, 8 prompt
__global__ __launch_bounds__(256) void k_wcast_all(
    const float* Wqkv, const float* Wo, const float* W1, const float* W2,
    const float* Wsk, const float* Wout, const float* Wsp, const float* Wcd,
    const float* Wpr, u16* __restrict__ WT)
{
    const int  nx[9]  = {24, 8, 32, 8, 8, 4, 8, 8, 8};
    const int  ny[9]  = {8, 8, 8, 32, 8, 8, 4, 4, 4};
    const int  cnt[9] = {768, 256, 1024, 1024, 64, 32, 32, 32, 32};
    const int  Kt[9]  = {512, 512, 512, 2048, 512, 512, 256, 256, 256};
    const int  Nt[9]  = {1536, 512, 2048, 512, 512, 256, 512, 512, 512};
    const long inS[9]  = {786432L, 262144L, 1048576L, 1048576L, 0L, 0L, 0L, 0L, 0L};
    const long outS[9] = {786432L, 262144L, 1048576L, 1048576L, 0L, 0L, 0L, 0L, 0L};
    const long wo[9]   = {WT_QKV, WT_WO, WT_W1, WT_W2, WT_SK, WT_OUT, WT_SPEC, WT_COND, WT_PR};
    const float* Ws[9] = {Wqkv, Wo, W1, W2, Wsk, Wout, Wsp, Wcd, Wpr};

    int t = blockIdx.x;
    int j = 0;
    #pragma unroll
    for (int s = 0; s < 9; s++) { if (t >= cnt[s] && j == s) { t -= cnt[s]; j = s + 1; } }
    int x = t % nx[j];
    int rest = t / nx[j];
    int y = rest % ny[j];
    int z = rest / ny[j];
    wcast_tile(Ws[j] + (long)z * inS[j], WT + wo[j] + (long)z * outS[j],
               Kt[j], Nt[j], x * 64, y * 64, threadIdx.x);
}

// transpose+cast with N bounds (activations); z<4 -> spec batch z, z>=4 -> cond batch z-4
__global__ __launch_bounds__(256) void k_acast2(const float* __restrict__ spec,
                                                const float* __restrict__ cond,
                                                u16* __restrict__ specO, u16* __restrict__ condO)
{
    __shared__ float t[64][65];
    const int K = DD, N = TT;
    int n0 = blockIdx.x * 64, k0 = blockIdx.y * 64;
    int z = blockIdx.z;
    const float* Wz = (z < 4) ? (spec + (long)z * DD * TT) : (cond + (long)(z - 4) * DD * TT);
    u16* Oz = (z < 4) ? (specO + (long)z * TT * DD) : (condO + (long)(z - 4) * TT * DD);
    int tid = threadIdx.x;
    #pragma unroll
    for (int p = 0; p < 16; p++) {
        int idx = tid + p * 256;
        int rk = idx >> 6, cn = idx & 63;
        int nn = n0 + cn; if (nn >= N) nn = N - 1;
        t[rk][cn] = Wz[(long)(k0 + rk) * N + nn];
    }
    __syncthreads();
    #pragma unroll
    for (int p = 0; p < 8; p++) {
        int idx = tid + p * 256;
        int nn = idx >> 5, k2 = (idx & 31) * 2;
        if (n0 + nn < N) {
            ushort2 u;
            u.x = f2bf(t[k2][nn]);
            u.y = f2bf(t[k2 + 1][nn]);
            *(ushort2*)&Oz[(long)(n0 + nn) * K + k0 + k2] = u;
        }
    }
}

// elementwise fp32 -> bf16 cast
__global__ void k_cast(const float4* __restrict__ in, ushort4* __restrict__ out, int n4)
{
    int i = blockIdx.x * 256 + threadIdx.x;
    if (i < n4) {
        float4 v = in[i];
        ushort4 u;
        u.x = f2bf(v.x); u.y = f2bf(v.y); u.z = f2bf(v.z); u.w = f2bf(v.w);
        out[i] = u;
    }
}

// ---------------- bf16 MFMA GEMM core (64x128, BK=64, 32x64/wave) ----------------
template<int RELU, int OUTBF, int ATOMIC>
__device__ __forceinline__ void mm64_body(
    const u16* __restrict__ A, const u16* __restrict__ Bt,
    const float* __restrict__ bias, void* __restrict__ Cp,
    int M, int N, int K, int kbase, int Ks, int addBias,
    int m0, int n0, u16* As, u16* Bs0, u16* Bs1, int tid)
{
    int w = tid >> 6, lane = tid & 63;
    int q = lane >> 4, r = lane & 15;
    int wm = w & 1, wn = w >> 1;
    f32x4 acc[2][4] = {};
    int ar0 = wm * 32 + r;
    int ar1 = ar0 + 16;
    int aoff0 = ar0 * 32 + (q ^ ((ar0 >> 1) & 3)) * 8;
    int aoff1 = ar1 * 32 + (q ^ ((ar1 >> 1) & 3)) * 8;
    u16* BsW[2] = {Bs0, Bs1};

    for (int k0 = kbase; k0 < kbase + Ks; k0 += 64) {
        __syncthreads();
        stage64c(A + k0, K, m0, M - 1, As, tid);
        stage64(Bt + (long)n0 * K + k0, K, Bs0, tid);
        stage64(Bt + (long)(n0 + 64) * K + k0, K, Bs1, tid);
        __syncthreads();
        #pragma unroll
        for (int kh = 0; kh < 2; kh++) {
            bf16x8 a0 = *(const bf16x8*)&As[kh * 2048 + aoff0];
            bf16x8 a1 = *(const bf16x8*)&As[kh * 2048 + aoff1];
            #pragma unroll
            for (int ni = 0; ni < 4; ni++) {
                int rr = ni * 16 + r;
                bf16x8 bv = *(const bf16x8*)&BsW[wn][kh * 2048 + rr * 32 + (q ^ ((rr >> 1) & 3)) * 8];
                acc[0][ni] = __builtin_amdgcn_mfma_f32_16x16x32_bf16(a0, bv, acc[0][ni], 0, 0, 0);
                acc[1][ni] = __builtin_amdgcn_mfma_f32_16x16x32_bf16(a1, bv, acc[1][ni], 0, 0, 0);
            }
        }
    }

    #pragma unroll
    for (int ni = 0; ni < 4; ni++) {
        int col = n0 + wn * 64 + ni * 16 + r;
        float bs = addBias ? bias[col] : 0.f;
        #pragma unroll
        for (int mi = 0; mi < 2; mi++) {
            #pragma unroll
            for (int reg = 0; reg < 4; reg++) {
                int grow = m0 + wm * 32 + mi * 16 + q * 4 + reg;
                if (grow >= M) continue;
                long off = (long)grow * N + col;
                float v = acc[mi][ni][reg] + bs;
                if (RELU) v = fmaxf(v, 0.f);
                if (ATOMIC)      atomicAdd((float*)Cp + off, v);
                else if (OUTBF)  ((u16*)Cp)[off] = f2bf(v);
                else             ((float*)Cp)[off] = v;
            }
        }
    }
}

template<int RELU, int OUTBF, int ATOMIC>
__global__ __launch_bounds__(256) void k_mm64(
    const u16* __restrict__ A, const u16* __restrict__ Bt,
    const float* __restrict__ bias, void* __restrict__ Cp,
    int M, int N, int K, int Ks)
{
    int mb = blockIdx.y * 8 + (blockIdx.x & 7);
    int m0 = mb * 64;
    if (m0 >= M) return;
    int n0 = (blockIdx.x >> 3) * 128;
    __shared__ u16 As[4096];
    __shared__ u16 Bs[2][4096];
    int kz = blockIdx.z;
    mm64_body<RELU, OUTBF, ATOMIC>(A, Bt, bias, Cp, M, N, K, kz * Ks, Ks,
                                   (!ATOMIC || kz == 0), m0, n0, As, Bs[0], Bs[1], threadIdx.x);
}

// three input projections in one launch (z selects job)
struct MM3Args {
    const u16* A0; const u16* A1; const u16* A2;
    const u16* B0; const u16* B1; const u16* B2;
    const float* b0; const float* b1; const float* b2;
    float* C0; float* C1; float* C2;
};
__global__ __launch_bounds__(256) void k_mm3(MM3Args a)
{
    int j = blockIdx.z;
    const u16* A  = (j == 0) ? a.A0 : (j == 1) ? a.A1 : a.A2;
    const u16* Bt = (j == 0) ? a.B0 : (j == 1) ? a.B1 : a.B2;
    const float* bias = (j == 0) ? a.b0 : (j == 1) ? a.b1 : a.b2;
    float* C = (j == 0) ? a.C0 : (j == 1) ? a.C1 : a.C2;
    int M = (j == 2) ? (BB * PP) : (BB * TT);
    int mb = blockIdx.y * 8 + (blockIdx.x & 7);
    int m0 = mb * 64;
    if (m0 >= M) return;
    int n0 = (blockIdx.x >> 3) * 128;
    __shared__ u16 As[4096];
    __shared__ u16 Bs[2][4096];
    mm64_body<0, 0, 0>(A, Bt, bias, C, M, CC, DD, 0, DD, 1, m0, n0, As, Bs[0], Bs[1], threadIdx.x);
}

// ---------------- QKV GEMM (XCD-swizzled): Q,K natural bf16 + V transposed ----------------
__global__ __launch_bounds__(256) void k_mmqkv64(
    const u16* __restrict__ A, const u16* __restrict__ Bt,
    const float* __restrict__ bias, u16* __restrict__ qkh, u16* __restrict__ vt,
    int M, int K)
{
    int mb = blockIdx.y * 8 + (blockIdx.x & 7);
    int m0 = mb * 64;
    if (m0 >= M) return;
    int n0 = (blockIdx.x >> 3) * 128;
    __shared__ u16 As[4096];
    __shared__ u16 Bs[2][4096];
    int tid = threadIdx.x;
    int w = tid >> 6, lane = tid & 63;
    int q = lane >> 4, r = lane & 15;
    int wm = w & 1, wn = w >> 1;
    f32x4 acc[2][4] = {};
    int ar0 = wm * 32 + r;
    int ar1 = ar0 + 16;
    int aoff0 = ar0 * 32 + (q ^ ((ar0 >> 1) & 3)) * 8;
    int aoff1 = ar1 * 32 + (q ^ ((ar1 >> 1) & 3)) * 8;

    for (int k0 = 0; k0 < K; k0 += 64) {
        __syncthreads();
        stage64c(A + k0, K, m0, M - 1, As, tid);
        stage64(Bt + (long)n0 * K + k0, K, Bs[0], tid);
        stage64(Bt + (long)(n0 + 64) * K + k0, K, Bs[1], tid);
        __syncthreads();
        #pragma unroll
        for (int kh = 0; kh < 2; kh++) {
            bf16x8 a0 = *(const bf16x8*)&As[kh * 2048 + aoff0];
            bf16x8 a1 = *(const bf16x8*)&As[kh * 2048 + aoff1];
            #pragma unroll
            for (int ni = 0; ni < 4; ni++) {
                int rr = ni * 16 + r;
                bf16x8 bv = *(const bf16x8*)&Bs[wn][kh * 2048 + rr * 32 + (q ^ ((rr >> 1) & 3)) * 8];
                acc[0][ni] = __builtin_amdgcn_mfma_f32_16x16x32_bf16(a0, bv, acc[0][ni], 0, 0, 0);
                acc[1][ni] = __builtin_amdgcn_mfma_f32_16x16x32_bf16(a1, bv, acc[1][ni], 0, 0, 0);
            }
        }
    }

    #pragma unroll
    for (int ni = 0; ni < 4; ni++) {
        int col = n0 + wn * 64 + ni * 16 + r;
        float bs = bias[col];
        #pragma unroll
        for (int mi = 0; mi < 2; mi++) {
            #pragma unroll
            for (int reg = 0; reg < 4; reg++) {
                int grow = m0 + wm * 32 + mi * 16 + q * 4 + reg;
                if (grow >= M) continue;
                float v = acc[mi][ni][reg] + bs;
                if (col < 1024) {
                    qkh[(long)grow * 1024 + col] = f2bf(v);
                } else {
                    int c2 = col - 1024;
                    int hh = c2 >> 6, dd = c2 & 63;
                    int bq = grow / LL;
                    int jj = grow - bq * LL;
                    vt[(((long)(bq * HH + hh)) * 64 + dd) * VTS + jj] = f2bf(v);
                }
            }
        }
    }
}

// ---------------- MFMA flash attention, fixed-base softmax ----------------
__global__ __launch_bounds__(256) void k_attn(const u16* __restrict__ qkh,
                                              const u16* __restrict__ vt,
                                              const int* __restrict__ meta,
                                              u16* __restrict__ aoh)
{
    __shared__ u16 Qs[4096], Ks[4096], Vts[4096], Ps[4096];
    int id = blockIdx.x;
    int h = id & 7;
    int rest = id >> 3;
    int b = rest & 3;
    int qt = rest >> 2;
    int tid = threadIdx.x;
    int w = tid >> 6, lane = tid & 63;
    int q = lane >> 4, r = lane & 15;
    int kend = meta[b] + meta[4 + b];
    int q0 = qt * 64;

    stage64(qkh + ((long)(b * LL + q0)) * 1024 + h * DH, 1024, Qs, tid);

    float lsum[4] = {0.f, 0.f, 0.f, 0.f};
    f32x4 O[4] = {};

    int arow = w * 16 + r;
    int aoff = arow * 32 + (q ^ ((arow >> 1) & 3)) * 8;

    for (int j0 = 0; j0 < kend; j0 += 64) {
        __syncthreads();
        stage64(qkh + ((long)(b * LL + j0)) * 1024 + CC + h * DH, 1024, Ks, tid);
        stage64(vt + (((long)(b * HH + h)) * 64) * VTS + j0, VTS, Vts, tid);
        __syncthreads();

        f32x4 sacc[4] = {};
        #pragma unroll
        for (int kh = 0; kh < 2; kh++) {
            bf16x8 aq = *(const bf16x8*)&Qs[kh * 2048 + aoff];
            #pragma unroll
            for (int ni = 0; ni < 4; ni++) {
                int rn = ni * 16 + r;
                bf16x8 bk = *(const bf16x8*)&Ks[kh * 2048 + rn * 32 + (q ^ ((rn >> 1) & 3)) * 8];
                sacc[ni] = __builtin_amdgcn_mfma_f32_16x16x32_bf16(aq, bk, sacc[ni], 0, 0, 0);
            }
        }

        #pragma unroll
        for (int reg = 0; reg < 4; reg++) {
            int prow = w * 16 + q * 4 + reg;
            int psw = (prow >> 1) & 3;
            #pragma unroll
            for (int ni = 0; ni < 4; ni++) {
                int jg = j0 + r + 16 * ni;
                float p = (jg < kend) ? __expf(sacc[ni][reg] * 0.125f) : 0.f;
                lsum[reg] += p;
                int c = r + 16 * ni;
                Ps[(c >> 5) * 2048 + prow * 32 + ((((c & 31) >> 3)) ^ psw) * 8 + (c & 7)] = f2bf(p);
            }
        }

        #pragma unroll
        for (int kh = 0; kh < 2; kh++) {
            bf16x8 ap = *(const bf16x8*)&Ps[kh * 2048 + aoff];
            #pragma unroll
            for (int ni = 0; ni < 4; ni++) {
                int rn = ni * 16 + r;
                bf16x8 bv = *(const bf16x8*)&Vts[kh * 2048 + rn * 32 + (q ^ ((rn >> 1) & 3)) * 8];
                O[ni] = __builtin_amdgcn_mfma_f32_16x16x32_bf16(ap, bv, O[ni], 0, 0, 0);
            }
        }
    }

    #pragma unroll
    for (int reg = 0; reg < 4; reg++) {
        float l = lsum[reg];
        #pragma unroll
        for (int off = 1; off < 16; off <<= 1) l += __shfl_xor(l, off, 64);
        int qr = q0 + w * 16 + q * 4 + reg;
        if (qr >= LL) continue;
        float inv = 1.f / l;
        #pragma unroll
        for (int ni = 0; ni < 4; ni++)
            aoh[((long)(b * LL + qr)) * CC + h * DH + r + 16 * ni] = f2bf(O[ni][reg] * inv);
    }
}

// ---------------- pack ----------------
__global__ void k_pack(const float* __restrict__ spec_h, const float* __restrict__ cond_h,
                       const float* __restrict__ prompt_h, const float* __restrict__ stepbuf,
                       const int* __restrict__ meta, float* __restrict__ x)
{
    int j = blockIdx.x, b = blockIdx.y;
    int pl = meta[b], sl = meta[4 + b];
    int tid = threadIdx.x;
    int reg = (j < pl) ? 0 : ((j < pl + sl) ? 1 : 2);
    int pos = (reg == 0) ? j + 1 : ((reg == 1) ? j - pl + 1 : j - pl - sl + 1);
    const float c1 = 9.210340371976184f / 255.f;
    for (int c = tid; c < CC; c += 256) {
        int i = (c < 256) ? c : c - 256;
        float f = expf(-c1 * (float)i);
        float a = (float)pos * f;
        float v = (c < 256) ? sinf(a) : cosf(a);
        if (reg == 0) {
            v += prompt_h[((long)(b * PP + j)) * CC + c] + stepbuf[4 * CC + c];
        } else if (reg == 1) {
            int t = j - pl;
            v += spec_h[((long)(b * TT + t)) * CC + c] + cond_h[((long)(b * TT + t)) * CC + c]
               + stepbuf[b * CC + c];
        }
        x[((long)(b * LL + j)) * CC + c] = v;
    }
}

// ---------------- LayerNorm -> bf16 ----------------
__global__ __launch_bounds__(256) void k_ln(float* __restrict__ x, const float* __restrict__ skip,
                                            const float* __restrict__ g, const float* __restrict__ bb,
                                            u16* __restrict__ xnh)
{
    long row = blockIdx.x;
    float* xr = x + row * CC;
    int tid = threadIdx.x;
    float v0 = xr[tid], v1 = xr[tid + 256];
    if (skip) {
        const float rs2 = 0.7071067811865476f;
        v0 = (v0 + skip[row * CC + tid]) * rs2;
        v1 = (v1 + skip[row * CC + tid + 256]) * rs2;
        xr[tid] = v0; xr[tid + 256] = v1;
    }
    float s = v0 + v1;
    for (int off = 32; off; off >>= 1) s += __shfl_down(s, off, 64);
    __shared__ float red[4];
    int wid = tid >> 6, lane = tid & 63;
    if (lane == 0) red[wid] = s;
    __syncthreads();
    float mean = (red[0] + red[1] + red[2] + red[3]) * (1.f / (float)CC);
    float d0 = v0 - mean, d1 = v1 - mean;
    float q = d0 * d0 + d1 * d1;
    for (int off = 32; off; off >>= 1) q += __shfl_down(q, off, 64);
    __syncthreads();
    if (lane == 0) red[wid] = q;
    __syncthreads();
    float var = (red[0] + red[1] + red[2] + red[3]) * (1.f / (float)CC);
    float rstd = rsqrtf(var + 1e-5f);
    xnh[row * CC + tid]       = f2bf(d0 * rstd * g[tid] + bb[tid]);
    xnh[row * CC + tid + 256] = f2bf(d1 * rstd * g[tid + 256] + bb[tid + 256]);
}

// ---------------- fused skip-accum + next-layer ln1 ----------------
__global__ __launch_bounds__(256) void k_accum_ln(
    float* __restrict__ x, float* __restrict__ fsum, float* __restrict__ skipdst,
    const float* __restrict__ skip, int self,
    const float* __restrict__ g, const float* __restrict__ bb,
    u16* __restrict__ xnh, u16* __restrict__ fsh, int first, int last)
{
    long row = blockIdx.x;
    int tid = threadIdx.x;
    long o0 = row * CC + tid, o1 = o0 + 256;
    float v0 = x[o0], v1 = x[o1];
    float f0, f1;
    if (first) { f0 = v0; f1 = v1; }
    else { f0 = fsum[o0] + v0; f1 = fsum[o1] + v1; }
    fsum[o0] = f0; fsum[o1] = f1;
    if (skipdst) { skipdst[o0] = v0; skipdst[o1] = v1; }
    if (last) {
        fsh[o0] = f2bf(f0 * 0.5f);
        fsh[o1] = f2bf(f1 * 0.5f);
        return;
    }
    const float rs2 = 0.7071067811865476f;
    if (self) {
        v0 *= 1.4142135623730951f; v1 *= 1.4142135623730951f;
        x[o0] = v0; x[o1] = v1;
    } else if (skip) {
        v0 = (v0 + skip[o0]) * rs2; v1 = (v1 + skip[o1]) * rs2;
        x[o0] = v0; x[o1] = v1;
    }
    float s = v0 + v1;
    for (int off = 32; off; off >>= 1) s += __shfl_down(s, off, 64);
    __shared__ float red[4];
    int wid = tid >> 6, lane = tid & 63;
    if (lane == 0) red[wid] = s;
    __syncthreads();
    float mean = (red[0] + red[1] + red[2] + red[3]) * (1.f / (float)CC);
    float d0 = v0 - mean, d1 = v1 - mean;
    float qv = d0 * d0 + d1 * d1;
    for (int off = 32; off; off >>= 1) qv += __shfl_down(qv, off, 64);
    __syncthreads();
    if (lane == 0) red[wid] = qv;
    __syncthreads();
    float var = (red[0] + red[1] + red[2] + red[3]) * (1.f / (float)CC);
    float rstd = rsqrtf(var + 1e-5f);
    xnh[o0] = f2bf(d0 * rstd * g[tid] + bb[tid]);
    xnh[o1] = f2bf(d1 * rstd * g[tid + 256] + bb[tid + 256]);
}

// ---------------- final gather + transpose ----------------
__global__ void k_gather(const float* __restrict__ z, const int* __restrict__ meta,
                         float* __restrict__ out)
{
    int i = blockIdx.x * 256 + threadIdx.x;
    int b = i / (DD * TT);
    int rdt = i % (DD * TT);
    int d = rdt / TT, t = rdt % TT;
    long row = (long)b * LL + meta[b] + t;
    out[i] = z[row * DD + d];
}

extern "C" void kernel_launch(void* const* d_in, const int* in_sizes, int n_in,
                              void* d_out, int out_size, void* d_ws, size_t ws_size,
                              hipStream_t stream)
{
    const float* spec     = (const float*)d_in[0];
    const void*  x_mask   = d_in[1];
    const float* dstep_in = (const float*)d_in[2];
    const float* cond     = (const float*)d_in[3];
    const float* prompt   = (const float*)d_in[5];
    const void*  p_mask   = d_in[6];
    const float* spec_W   = (const float*)d_in[7];
    const float* spec_b   = (const float*)d_in[8];
    const float* cond_W   = (const float*)d_in[9];
    const float* cond_b   = (const float*)d_in[10];
    const float* prompt_W = (const float*)d_in[11];
    const float* prompt_b = (const float*)d_in[12];
    const float* mlp_W1   = (const float*)d_in[13];
    const float* mlp_b1   = (const float*)d_in[14];
    const float* mlp_W2   = (const float*)d_in[15];
    const float* mlp_b2   = (const float*)d_in[16];
    const float* out_W    = (const float*)d_in[17];
    const float* out_b    = (const float*)d_in[18];
    const float* skip_W   = (const float*)d_in[19];
    const float* skip_b   = (const float*)d_in[20];
    const float* Wqkv     = (const float*)d_in[21];
    const float* bqkv     = (const float*)d_in[22];
    const float* Wo       = (const float*)d_in[23];
    const float* bo       = (const float*)d_in[24];
    const float* ln1_g    = (const float*)d_in[25];
    const float* ln1_b    = (const float*)d_in[26];
    const float* ln2_g    = (const float*)d_in[27];
    const float* ln2_b    = (const float*)d_in[28];
    const float* ffn_W1   = (const float*)d_in[29];
    const float* ffn_b1   = (const float*)d_in[30];
    const float* ffn_W2   = (const float*)d_in[31];
    const float* ffn_b2   = (const float*)d_in[32];

    float* W  = (float*)d_ws;
    int* meta = (int*)d_ws;
    float* stepbuf = W + OFF_STEP;
    float* HB  = W + OFF_HB;
    float* S0  = W + OFF_S0;
    float* S1  = W + OFF_S1;
    float* FS  = W + OFF_FS;
    float* X   = W + OFF_X;
    u16*   QKHh = (u16*)(W + OFF_BIG);
    u16*   VTh  = (u16*)(W + OFF_VT);
    u16*   BIGh = (u16*)(W + OFF_BIG);
    u16*   SPECAh = (u16*)(W + OFF_BIG);
    u16*   CONDAh = (u16*)(W + OFF_BIG + 512000L);
    u16*   PRAh   = (u16*)(W + OFF_BIG + 1024000L);
    float* Z   = W + OFF_Z;
    u16*   XNh = (u16*)(W + OFF_XNH);
    u16*   AOh = (u16*)(W + OFF_AOH);
    u16*   FSh = (u16*)(W + OFF_FSH);
    u16*   WT  = (u16*)(W + OFF_WT);

    k_meta<<<1, 256, 0, stream>>>((const unsigned*)p_mask, (const unsigned*)x_mask, meta);
    k_step1<<<dim3(16, 5), 256, 0, stream>>>(dstep_in, mlp_W1, mlp_b1, HB);
    k_step2<<<dim3(8, 5), 256, 0, stream>>>(HB, mlp_W2, mlp_b2, stepbuf);

    // ALL weight transposes+casts in one launch (3264 blocks)
    k_wcast_all<<<3264, 256, 0, stream>>>(Wqkv, Wo, ffn_W1, ffn_W2, skip_W, out_W,
                                          spec_W, cond_W, prompt_W, WT);

    // activation casts: spec+cond transpose in one launch; prompt elementwise
    k_acast2<<<dim3(16, 4, 8), 256, 0, stream>>>(spec, cond, SPECAh, CONDAh);
    k_cast<<<300, 256, 0, stream>>>((const float4*)prompt, (ushort4*)PRAh, BB * PP * DD / 4);

    // three input projections in one launch
    MM3Args m3;
    m3.A0 = SPECAh; m3.A1 = CONDAh; m3.A2 = PRAh;
    m3.B0 = WT + WT_SPEC; m3.B1 = WT + WT_COND; m3.B2 = WT + WT_PR;
    m3.b0 = spec_b; m3.b1 = cond_b; m3.b2 = prompt_b;
    m3.C0 = S0; m3.C1 = S1; m3.C2 = FS;
    k_mm3<<<dim3(32, 8, 3), 256, 0, stream>>>(m3);

    k_pack<<<dim3(LL, BB), 256, 0, stream>>>(S0, S1, FS, stepbuf, meta, X);

    const int Mrows = BB * LL; // 5200
    k_ln<<<Mrows, 256, 0, stream>>>(X, nullptr, ln1_g, ln1_b, XNh);
    for (int i = 0; i < 4; i++) {
        k_mmqkv64<<<dim3(96, 11), 256, 0, stream>>>(XNh, WT + WT_QKV + (long)i * CC * H3,
            bqkv + i * H3, QKHh, VTh, Mrows, CC);
        k_attn<<<672, 256, 0, stream>>>(QKHh, VTh, meta, AOh);
        k_mm64<0, 0, 1><<<dim3(32, 11, 2), 256, 0, stream>>>(AOh, WT + WT_WO + (long)i * CC * CC,
            bo + i * CC, X, Mrows, CC, CC, 256);
        k_ln<<<Mrows, 256, 0, stream>>>(X, nullptr, ln2_g + i * CC, ln2_b + i * CC, XNh);
        k_mm64<1, 1, 0><<<dim3(128, 11), 256, 0, stream>>>(XNh, WT + WT_W1 + (long)i * CC * FF,
            ffn_b1 + i * FF, BIGh, Mrows, FF, CC, CC);
        k_mm64<0, 0, 1><<<dim3(32, 11, 2), 256, 0, stream>>>(BIGh, WT + WT_W2 + (long)i * FF * CC,
            ffn_b2 + i * CC, X, Mrows, CC, FF, 1024);
        float* skipDst = (i == 0) ? S0 : nullptr;
        const float* skipNext = (i == 2) ? S0 : nullptr;
        int selfNext = (i == 1) ? 1 : 0;
        k_accum_ln<<<Mrows, 256, 0, stream>>>(X, FS, skipDst, skipNext, selfNext,
            ln1_g + (i + 1 < 4 ? (i + 1) : 0) * CC, ln1_b + (i + 1 < 4 ? (i + 1) : 0) * CC,
            XNh, FSh, i == 0, i == 3);
    }

    // y = relu((fsum*0.5) @ skip_W + skip_b) -> XNh (bf16), direct store
    k_mm64<1, 1, 0><<<dim3(32, 11), 256, 0, stream>>>(FSh, WT + WT_SK, skip_b, XNh, Mrows, CC, CC, CC);
    // z = y @ out_W + out_b -> Z, direct store (no zero, no atomics)
    k_mm64<0, 0, 0><<<dim3(16, 11), 256, 0, stream>>>(XNh, WT + WT_OUT, out_b, Z, Mrows, DD, CC, CC);

    k_gather<<<4000, 256, 0, stream>>>(Z, meta, (float*)d_out);
    (void)in_sizes; (void)n_in; (void)out_size; (void)ws_size;
}